// Round 2
// baseline (598.093 us; speedup 1.0000x reference)
//
#include <hip/hip_runtime.h>
#include <hip/hip_bf16.h>
#include <stdint.h>

#define B_   8
#define C_   384
#define HEAD_ 8
#define CH_  48
#define HW_  16384

typedef __attribute__((ext_vector_type(4))) float f32x4;
typedef __attribute__((ext_vector_type(8))) short short8;
typedef __attribute__((ext_vector_type(8))) unsigned short u16x8;
typedef __attribute__((ext_vector_type(4))) unsigned short u16x4;

__device__ __forceinline__ float bf2f(unsigned short u) {
  union { float f; uint32_t i; } v; v.i = ((uint32_t)u) << 16; return v.f;
}
__device__ __forceinline__ unsigned short f2bf(float f) {
  union { float f; uint32_t i; } v; v.f = f;
  uint32_t x = v.i;
  return (unsigned short)((x + 0x7fffu + ((x >> 16) & 1u)) >> 16);
}

// async global->LDS, 16B per lane. LDS dest must be wave-uniform base (+lane*16 implicit).
__device__ __forceinline__ void gload_lds16(const void* gsrc, void* ldst) {
  const __attribute__((address_space(1))) void* g =
      (const __attribute__((address_space(1))) void*)(uintptr_t)gsrc;
  __attribute__((address_space(3))) void* l =
      (__attribute__((address_space(3))) void*)(uint32_t)(uintptr_t)ldst;
  __builtin_amdgcn_global_load_lds(g, l, 16, 0, 0);
}

// ---------------- K1: convert x -> xb (c-major bf16) and xbT (n-major bf16) ----------------
__global__ __launch_bounds__(256) void k_convert(const float* __restrict__ x,
                                                 unsigned short* __restrict__ xb,
                                                 unsigned short* __restrict__ xbT) {
  __shared__ unsigned short tile[64][65];
  const int n0 = blockIdx.x * 64, c0 = blockIdx.y * 64, b = blockIdx.z;
  const int t = threadIdx.x;
  const int row = t >> 2;          // c-local 0..63
  const int col = (t & 3) * 16;    // n-local 0,16,32,48
  const float* src = x + ((size_t)b * C_ + (c0 + row)) * HW_ + n0 + col;
  unsigned short tmp[16];
#pragma unroll
  for (int i = 0; i < 4; ++i) {
    float4 v = *(const float4*)(src + i * 4);
    tmp[i * 4 + 0] = f2bf(v.x); tmp[i * 4 + 1] = f2bf(v.y);
    tmp[i * 4 + 2] = f2bf(v.z); tmp[i * 4 + 3] = f2bf(v.w);
  }
  unsigned short* dst = xb + ((size_t)b * C_ + (c0 + row)) * HW_ + n0 + col;
  u16x8 o0, o1;
#pragma unroll
  for (int j = 0; j < 8; ++j) { o0[j] = tmp[j]; o1[j] = tmp[8 + j]; }
  *(u16x8*)dst = o0;
  *(u16x8*)(dst + 8) = o1;
#pragma unroll
  for (int j = 0; j < 16; ++j) tile[row][col + j] = tmp[j];
  __syncthreads();
  const int nrow = t >> 2, cc = (t & 3) * 16;
  u16x8 p0, p1;
#pragma unroll
  for (int j = 0; j < 8; ++j) { p0[j] = tile[cc + j][nrow]; p1[j] = tile[cc + 8 + j][nrow]; }
  unsigned short* dT = xbT + ((size_t)b * HW_ + (n0 + nrow)) * C_ + c0 + cc;
  *(u16x8*)dT = p0;
  *(u16x8*)(dT + 8) = p1;
}

// ---------------- K1b: weights -> bf16 (wq,wk stacked; wv transposed; wo) ----------------
__global__ __launch_bounds__(256) void k_convw(const float* __restrict__ wq, const float* __restrict__ wk,
                                               const float* __restrict__ wv, const float* __restrict__ wo,
                                               unsigned short* __restrict__ wqk,
                                               unsigned short* __restrict__ wvT,
                                               unsigned short* __restrict__ wob) {
  int i = blockIdx.x * 256 + threadIdx.x;
  if (i >= C_ * C_) return;
  int r = i / C_, c = i % C_;
  wqk[i] = f2bf(wq[i]);
  wqk[C_ * C_ + i] = f2bf(wk[i]);
  wob[i] = f2bf(wo[i]);
  wvT[(size_t)c * C_ + r] = f2bf(wv[i]);
}

// ---------------- K2: G_b = X_b X_b^T (upper tiles only), K-split with atomics ----------------
__global__ __launch_bounds__(256) void k_G(const unsigned short* __restrict__ xb,
                                           float* __restrict__ G) {
  __shared__ unsigned short ldsA[128 * 64];
  __shared__ unsigned short ldsB[128 * 64];
  const int s = blockIdx.x;
  const int xcd = s & 7, slot = s >> 3;       // swizzle: group (b,kc) pinned to one XCD
  const int gq = slot / 6, tile = slot - gq * 6;
  const int g = gq * 8 + xcd;                 // 0..63
  const int b = g >> 3, kc = g & 7;
  int ti, tj;
  if      (tile == 0) { ti = 0; tj = 0; }
  else if (tile == 1) { ti = 0; tj = 1; }
  else if (tile == 2) { ti = 0; tj = 2; }
  else if (tile == 3) { ti = 1; tj = 1; }
  else if (tile == 4) { ti = 1; tj = 2; }
  else                { ti = 2; tj = 2; }
  const unsigned short* Ar = xb + ((size_t)b * C_ + ti * 128) * HW_ + kc * 2048;
  const unsigned short* Br = xb + ((size_t)b * C_ + tj * 128) * HW_ + kc * 2048;
  const int tid = threadIdx.x, lane = tid & 63, wid = tid >> 6;
  const f32x4 fz = {0.f, 0.f, 0.f, 0.f};
  f32x4 acc[4][4];
#pragma unroll
  for (int i = 0; i < 4; ++i)
#pragma unroll
    for (int j = 0; j < 4; ++j) acc[i][j] = fz;
  for (int st = 0; st < 32; ++st) {
    __syncthreads();
#pragma unroll
    for (int i = 0; i < 4; ++i) {
      const int flat = i * 256 + tid;
      const int lbase = (i * 256 + wid * 64) * 8;
      gload_lds16(Ar + (size_t)(flat >> 3) * HW_ + st * 64 + (flat & 7) * 8, ldsA + lbase);
      gload_lds16(Br + (size_t)(flat >> 3) * HW_ + st * 64 + (flat & 7) * 8, ldsB + lbase);
    }
    __syncthreads();
    const int ml = (wid >> 1) * 64, nl = (wid & 1) * 64;
#pragma unroll
    for (int kk = 0; kk < 2; ++kk) {
      short8 af[4], bf[4];
      const int ko = kk * 32 + (lane >> 4) * 8;
#pragma unroll
      for (int mt = 0; mt < 4; ++mt)
        af[mt] = *(const short8*)(ldsA + (ml + mt * 16 + (lane & 15)) * 64 + ko);
#pragma unroll
      for (int nt = 0; nt < 4; ++nt)
        bf[nt] = *(const short8*)(ldsB + (nl + nt * 16 + (lane & 15)) * 64 + ko);
#pragma unroll
      for (int mt = 0; mt < 4; ++mt)
#pragma unroll
        for (int nt = 0; nt < 4; ++nt)
          acc[mt][nt] = __builtin_amdgcn_mfma_f32_16x16x32_bf16(af[mt], bf[nt], acc[mt][nt], 0, 0, 0);
    }
  }
  float* Gp = G + ((size_t)b * C_ + ti * 128 + (wid >> 1) * 64) * C_ + tj * 128 + (wid & 1) * 64;
#pragma unroll
  for (int mt = 0; mt < 4; ++mt)
#pragma unroll
    for (int nt = 0; nt < 4; ++nt) {
      const int r0 = mt * 16 + (lane >> 4) * 4, cc = nt * 16 + (lane & 15);
#pragma unroll
      for (int r = 0; r < 4; ++r)
        atomicAdd(Gp + (size_t)(r0 + r) * C_ + cc, acc[mt][nt][r]);
    }
}

// ---------------- K2b: mirror symmetric G and cast to bf16 ----------------
__global__ __launch_bounds__(256) void k_gsym(const float* __restrict__ G,
                                              unsigned short* __restrict__ Gbf) {
  int idx = blockIdx.x * 256 + threadIdx.x;
  if (idx >= B_ * C_ * C_) return;
  int b = idx / (C_ * C_), rem = idx % (C_ * C_);
  int i = rem / C_, j = rem % C_;
  float v = (i <= j) ? G[(size_t)b * C_ * C_ + (size_t)i * C_ + j]
                     : G[(size_t)b * C_ * C_ + (size_t)j * C_ + i];
  Gbf[idx] = f2bf(v);
}

// ---------------- small GEMM: C[m,n] = sum_k A[m,k] * B[n,k], per-batch B and C ----------------
__global__ __launch_bounds__(64) void k_bt64(const unsigned short* __restrict__ A,
                                             const unsigned short* __restrict__ Bb,
                                             unsigned short* __restrict__ Cb,
                                             int bstrideB, int bstrideC) {
  const int m0 = blockIdx.x * 64, n0 = blockIdx.y * 64, b = blockIdx.z;
  const int lane = threadIdx.x;
  const unsigned short* Bp = Bb + (size_t)b * bstrideB;
  const f32x4 fz = {0.f, 0.f, 0.f, 0.f};
  f32x4 acc[4][4];
#pragma unroll
  for (int i = 0; i < 4; ++i)
#pragma unroll
    for (int j = 0; j < 4; ++j) acc[i][j] = fz;
  for (int k = 0; k < C_; k += 32) {
    const int ko = k + (lane >> 4) * 8;
    short8 af[4], bf[4];
#pragma unroll
    for (int mt = 0; mt < 4; ++mt)
      af[mt] = *(const short8*)(A + (size_t)(m0 + mt * 16 + (lane & 15)) * C_ + ko);
#pragma unroll
    for (int nt = 0; nt < 4; ++nt)
      bf[nt] = *(const short8*)(Bp + (size_t)(n0 + nt * 16 + (lane & 15)) * C_ + ko);
#pragma unroll
    for (int mt = 0; mt < 4; ++mt)
#pragma unroll
      for (int nt = 0; nt < 4; ++nt)
        acc[mt][nt] = __builtin_amdgcn_mfma_f32_16x16x32_bf16(af[mt], bf[nt], acc[mt][nt], 0, 0, 0);
  }
  unsigned short* Cp = Cb + (size_t)b * bstrideC;
#pragma unroll
  for (int mt = 0; mt < 4; ++mt)
#pragma unroll
    for (int nt = 0; nt < 4; ++nt) {
      const int cc = n0 + nt * 16 + (lane & 15);
      const int r0 = m0 + mt * 16 + (lane >> 4) * 4;
#pragma unroll
      for (int r = 0; r < 4; ++r)
        Cp[(size_t)(r0 + r) * C_ + cc] = f2bf(acc[mt][nt][r]);
    }
}

// ---------------- K3: inverse row norms 1/max(sqrt(T[r].W[r]), eps) ----------------
__global__ __launch_bounds__(256) void k_norm(const unsigned short* __restrict__ Tbf,
                                              const unsigned short* __restrict__ wqk,
                                              float* __restrict__ rnorm) {
  const int gw = (blockIdx.x * 256 + threadIdx.x) >> 6;  // 0..6143
  const int lane = threadIdx.x & 63;
  const int b = gw / 768, r = gw % 768;
  const unsigned short* tp = Tbf + ((size_t)b * 768 + r) * C_;
  const unsigned short* wp = wqk + (size_t)r * C_;
  float s = 0.f;
#pragma unroll
  for (int j = 0; j < 6; ++j) {
    int idx = lane + j * 64;
    s += bf2f(tp[idx]) * bf2f(wp[idx]);
  }
#pragma unroll
  for (int off = 32; off > 0; off >>= 1) s += __shfl_xor(s, off);
  if (lane == 0) rnorm[gw] = 1.f / fmaxf(sqrtf(s), 1e-12f);
}

// ---------------- K4: per-(b,h): S = Tq_h Wk_h^T; softmax; M1T = (attn Wv_h)^T ----------------
__global__ __launch_bounds__(64) void k_attn(const unsigned short* __restrict__ Tbf,
                                             const unsigned short* __restrict__ wqk,
                                             const float* __restrict__ rnorm,
                                             const float* __restrict__ temp,
                                             const unsigned short* __restrict__ wvT,
                                             unsigned short* __restrict__ M1T) {
  const int bh = blockIdx.x, b = bh >> 3, h = bh & 7;
  const int lane = threadIdx.x;
  __shared__ float S[48][49];
  __shared__ unsigned short P[48][64];   // attn in bf16, k-padded to 64 with zeros
  const f32x4 fz = {0.f, 0.f, 0.f, 0.f};
  f32x4 acc[3][3];
#pragma unroll
  for (int i = 0; i < 3; ++i)
#pragma unroll
    for (int j = 0; j < 3; ++j) acc[i][j] = fz;
  const unsigned short* Aq = Tbf + ((size_t)b * 768 + h * 48) * C_;
  const unsigned short* Bk = wqk + (size_t)(384 + h * 48) * C_;
  for (int k = 0; k < C_; k += 32) {
    const int ko = k + (lane >> 4) * 8;
    short8 af[3], bf[3];
#pragma unroll
    for (int mt = 0; mt < 3; ++mt)
      af[mt] = *(const short8*)(Aq + (size_t)(mt * 16 + (lane & 15)) * C_ + ko);
#pragma unroll
    for (int nt = 0; nt < 3; ++nt)
      bf[nt] = *(const short8*)(Bk + (size_t)(nt * 16 + (lane & 15)) * C_ + ko);
#pragma unroll
    for (int mt = 0; mt < 3; ++mt)
#pragma unroll
      for (int nt = 0; nt < 3; ++nt)
        acc[mt][nt] = __builtin_amdgcn_mfma_f32_16x16x32_bf16(af[mt], bf[nt], acc[mt][nt], 0, 0, 0);
  }
#pragma unroll
  for (int mt = 0; mt < 3; ++mt)
#pragma unroll
    for (int nt = 0; nt < 3; ++nt) {
      const int r0 = mt * 16 + (lane >> 4) * 4, cc = nt * 16 + (lane & 15);
#pragma unroll
      for (int r = 0; r < 4; ++r) S[r0 + r][cc] = acc[mt][nt][r];
    }
  __syncthreads();
  const float th = temp[h];
  const float* rq = rnorm + b * 768 + h * 48;
  const float* rk = rnorm + b * 768 + 384 + h * 48;
  const float rkl = (lane < 48) ? rk[lane] : 0.f;
  for (int r = 0; r < 48; ++r) {
    float v = (lane < 48) ? S[r][lane] * rq[r] * rkl * th : -3.0e38f;
    float mx = v;
#pragma unroll
    for (int off = 32; off > 0; off >>= 1) mx = fmaxf(mx, __shfl_xor(mx, off));
    float e = (lane < 48) ? __expf(v - mx) : 0.f;
    float sm = e;
#pragma unroll
    for (int off = 32; off > 0; off >>= 1) sm += __shfl_xor(sm, off);
    P[r][lane] = (lane < 48) ? f2bf(e / sm) : (unsigned short)0;
  }
  __syncthreads();
  unsigned short* outp = M1T + (size_t)b * C_ * C_;
  const int jcol = lane & 15;
  for (int nt = 0; nt < 24; ++nt) {
    const int j = nt * 16 + jcol;
    f32x4 a2[3];
    a2[0] = fz; a2[1] = fz; a2[2] = fz;
#pragma unroll
    for (int kk = 0; kk < 2; ++kk) {
      const int kbase = kk * 32 + (lane >> 4) * 8;
      int gk = h * 48 + kbase;
      if (gk > 376) gk = 376;          // clamp: P==0 there so values don't matter
      const short8 bv = *(const short8*)(wvT + (size_t)j * C_ + gk);
#pragma unroll
      for (int mt = 0; mt < 3; ++mt) {
        const short8 av = *(const short8*)(&P[mt * 16 + (lane & 15)][kbase]);
        a2[mt] = __builtin_amdgcn_mfma_f32_16x16x32_bf16(av, bv, a2[mt], 0, 0, 0);
      }
    }
#pragma unroll
    for (int mt = 0; mt < 3; ++mt) {
      const int c0l = mt * 16 + (lane >> 4) * 4;
      u16x4 pk;
#pragma unroll
      for (int r = 0; r < 4; ++r) pk[r] = f2bf(a2[mt][r]);
      *(u16x4*)(outp + (size_t)j * C_ + h * 48 + c0l) = pk;
    }
  }
}

// ---------------- K6: final[b][o][n] = sum_c xbT[b][n][c] * Wf[b][o][c], fp32 out ----------------
__global__ __launch_bounds__(256) void k_F(const unsigned short* __restrict__ xbT,
                                           const unsigned short* __restrict__ Wf,
                                           float* __restrict__ out) {
  __shared__ unsigned short ldsA[128 * 64];
  __shared__ unsigned short ldsB[128 * 64];
  const int s = blockIdx.x;
  const int xcd = s & 7, slot = s >> 3;     // groups of 3 o-tiles share one n-panel on one XCD
  const int gq = slot / 3, t = slot - gq * 3;
  const int g = gq * 8 + xcd;               // 0..1023
  const int b = g >> 7, m = g & 127;
  const unsigned short* Ar = xbT + ((size_t)b * HW_ + m * 128) * C_;
  const unsigned short* Br = Wf + ((size_t)b * C_ + t * 128) * C_;
  const int tid = threadIdx.x, lane = tid & 63, wid = tid >> 6;
  const f32x4 fz = {0.f, 0.f, 0.f, 0.f};
  f32x4 acc[4][4];
#pragma unroll
  for (int i = 0; i < 4; ++i)
#pragma unroll
    for (int j = 0; j < 4; ++j) acc[i][j] = fz;
  for (int st = 0; st < 6; ++st) {
    __syncthreads();
#pragma unroll
    for (int i = 0; i < 4; ++i) {
      const int flat = i * 256 + tid;
      const int lbase = (i * 256 + wid * 64) * 8;
      gload_lds16(Ar + (size_t)(flat >> 3) * C_ + st * 64 + (flat & 7) * 8, ldsA + lbase);
      gload_lds16(Br + (size_t)(flat >> 3) * C_ + st * 64 + (flat & 7) * 8, ldsB + lbase);
    }
    __syncthreads();
    const int ml = (wid >> 1) * 64, nl = (wid & 1) * 64;
#pragma unroll
    for (int kk = 0; kk < 2; ++kk) {
      short8 af[4], bf[4];
      const int ko = kk * 32 + (lane >> 4) * 8;
#pragma unroll
      for (int mt = 0; mt < 4; ++mt)
        af[mt] = *(const short8*)(ldsA + (ml + mt * 16 + (lane & 15)) * 64 + ko);
#pragma unroll
      for (int nt = 0; nt < 4; ++nt)
        bf[nt] = *(const short8*)(ldsB + (nl + nt * 16 + (lane & 15)) * 64 + ko);
#pragma unroll
      for (int mt = 0; mt < 4; ++mt)
#pragma unroll
        for (int nt = 0; nt < 4; ++nt)
          acc[mt][nt] = __builtin_amdgcn_mfma_f32_16x16x32_bf16(af[mt], bf[nt], acc[mt][nt], 0, 0, 0);
    }
  }
  const int o0 = t * 128 + (wid & 1) * 64;
  const int n0 = m * 128 + (wid >> 1) * 64;
  float* ob = out + (size_t)b * C_ * HW_;
#pragma unroll
  for (int mt = 0; mt < 4; ++mt)
#pragma unroll
    for (int nt = 0; nt < 4; ++nt) {
      const int o = o0 + nt * 16 + (lane & 15);
      const int nn = n0 + mt * 16 + (lane >> 4) * 4;
      *(f32x4*)(ob + (size_t)o * HW_ + nn) = acc[mt][nt];
    }
}

extern "C" void kernel_launch(void* const* d_in, const int* in_sizes, int n_in,
                              void* d_out, int out_size, void* d_ws, size_t ws_size,
                              hipStream_t stream) {
  const float* x    = (const float*)d_in[0];
  const float* wq   = (const float*)d_in[1];
  const float* wk   = (const float*)d_in[2];
  const float* wv   = (const float*)d_in[3];
  const float* wo   = (const float*)d_in[4];
  const float* temp = (const float*)d_in[5];
  float* out = (float*)d_out;

  char* w = (char*)d_ws;
  unsigned short* xb  = (unsigned short*)w; w += (size_t)B_ * C_ * HW_ * 2;   // 100.7 MB
  unsigned short* xbT = (unsigned short*)w; w += (size_t)B_ * C_ * HW_ * 2;   // 100.7 MB
  float*          G   = (float*)w;          w += (size_t)B_ * C_ * C_ * 4;    // 4.7 MB
  unsigned short* Gbf = (unsigned short*)w; w += (size_t)B_ * C_ * C_ * 2;
  unsigned short* wqk = (unsigned short*)w; w += (size_t)2 * C_ * C_ * 2;
  unsigned short* wvT = (unsigned short*)w; w += (size_t)C_ * C_ * 2;
  unsigned short* wob = (unsigned short*)w; w += (size_t)C_ * C_ * 2;
  unsigned short* Tbf = (unsigned short*)w; w += (size_t)B_ * 2 * C_ * C_ * 2;
  float*          rno = (float*)w;          w += (size_t)B_ * 768 * 4;
  unsigned short* M1T = (unsigned short*)w; w += (size_t)B_ * C_ * C_ * 2;
  unsigned short* Wfb = (unsigned short*)w; w += (size_t)B_ * C_ * C_ * 2;

  hipMemsetAsync(G, 0, (size_t)B_ * C_ * C_ * 4, stream);
  k_convert<<<dim3(HW_ / 64, C_ / 64, B_), 256, 0, stream>>>(x, xb, xbT);
  k_convw<<<(C_ * C_ + 255) / 256, 256, 0, stream>>>(wq, wk, wv, wo, wqk, wvT, wob);
  k_G<<<384, 256, 0, stream>>>(xb, G);
  k_gsym<<<(B_ * C_ * C_ + 255) / 256, 256, 0, stream>>>(G, Gbf);
  k_bt64<<<dim3(12, 6, B_), 64, 0, stream>>>(wqk, Gbf, Tbf, C_ * C_, 2 * C_ * C_);
  k_norm<<<1536, 256, 0, stream>>>(Tbf, wqk, rno);
  k_attn<<<64, 64, 0, stream>>>(Tbf, wqk, rno, temp, wvT, M1T);
  k_bt64<<<dim3(6, 6, B_), 64, 0, stream>>>(wob, M1T, Wfb, C_ * C_, C_ * C_);
  k_F<<<3072, 256, 0, stream>>>(xbT, Wfb, out);
}